// Round 3
// baseline (156.293 us; speedup 1.0000x reference)
//
#include <hip/hip_runtime.h>

// Problem constants
#define NROWS 8192   // 4 * 2048
#define DIM   512
#define NT    64                    // 8192 / 128 tiles per side
#define NTRI  (NT * (NT + 1) / 2)   // 2080 upper-triangular tile blocks
#define NACC  64                    // accumulator slots (contention spread)

using bf16x8 = __attribute__((ext_vector_type(8))) __bf16;
using f32x4  = __attribute__((ext_vector_type(4))) float;

// round-to-nearest-even fp32 -> bf16 bits
__device__ __forceinline__ ushort f2bf(float f) {
    unsigned u = __float_as_uint(f);
    unsigned r = u + 0x7fffu + ((u >> 16) & 1u);
    return (ushort)(r >> 16);
}

// Kernel 1: fp32 row norms + fp32->bf16 conversion; zeroes acc slots + counter.
// One wave per row (512 elems = 64 lanes x 8).
__global__ __launch_bounds__(256) void norm_convert_kernel(
    const float* __restrict__ X, ushort* __restrict__ Xb,
    float* __restrict__ norms, float* __restrict__ acc,
    unsigned* __restrict__ counter)
{
    const int tid  = threadIdx.x;
    const int lane = tid & 63;
    const int w    = tid >> 6;
    const int row  = blockIdx.x * 4 + w;

    if (blockIdx.x == 0) {
        if (tid < NACC) acc[tid] = 0.0f;
        if (tid == NACC) *counter = 0u;
    }

    const float* xr = X + (size_t)row * DIM + lane * 8;
    float4 v0 = *(const float4*)xr;
    float4 v1 = *(const float4*)(xr + 4);

    float s = 0.0f;
    s = fmaf(v0.x, v0.x, s); s = fmaf(v0.y, v0.y, s);
    s = fmaf(v0.z, v0.z, s); s = fmaf(v0.w, v0.w, s);
    s = fmaf(v1.x, v1.x, s); s = fmaf(v1.y, v1.y, s);
    s = fmaf(v1.z, v1.z, s); s = fmaf(v1.w, v1.w, s);

    union { ushort u16[8]; uint4 v; } pk;
    pk.u16[0] = f2bf(v0.x); pk.u16[1] = f2bf(v0.y);
    pk.u16[2] = f2bf(v0.z); pk.u16[3] = f2bf(v0.w);
    pk.u16[4] = f2bf(v1.x); pk.u16[5] = f2bf(v1.y);
    pk.u16[6] = f2bf(v1.z); pk.u16[7] = f2bf(v1.w);
    *(uint4*)(Xb + (size_t)row * DIM + lane * 8) = pk.v;

    #pragma unroll
    for (int off = 32; off > 0; off >>= 1) s += __shfl_down(s, off, 64);
    if (lane == 0) norms[row] = s;
}

// Kernel 2: upper-triangular tiled X·X^T (bf16 MFMA) + fused sqrt/exp/sum
// epilogue + last-block finalize. 128x128 tile/block, 4 waves, 64x64
// quadrant/wave, BK=32. Register-prefetch double-buffered pipeline.
//
// LDS layout: XOR-swizzled. 16B chunk c (k-chunk) of row r is stored at
// column position c ^ ((r>>1)&3). Bank base of a 16B access by 16-lane
// group: 16*(r&1) + 4*(c ^ ((r>>1)&3)) -> reads exactly 2-way (free, m136),
// writes phase-conflict-free, LDS stays 32KB (4 blocks/CU).
__global__ __launch_bounds__(256, 4) void pair_loss_gemm_kernel(
    const ushort* __restrict__ Xb, const float* __restrict__ norms,
    float* __restrict__ acc, unsigned* __restrict__ counter,
    float* __restrict__ out)
{
    __shared__ __align__(16) ushort As0[128 * 32];
    __shared__ __align__(16) ushort As1[128 * 32];
    __shared__ __align__(16) ushort Bs0[128 * 32];
    __shared__ __align__(16) ushort Bs1[128 * 32];
    __shared__ float wsum[4];
    __shared__ int   is_last;

    // decode linear block id -> upper-triangular (bi, bj), bi <= bj
    int t = blockIdx.x, bi = 0;
    while (t >= (NT - bi)) { t -= (NT - bi); bi++; }
    const int bj = bi + t;

    const int tid  = threadIdx.x;
    const int lane = tid & 63;
    const int w    = tid >> 6;

    const int rowA = bi * 128;
    const int rowB = bj * 128;

    f32x4 accv[4][4];
    const f32x4 zero = {0.0f, 0.0f, 0.0f, 0.0f};
    #pragma unroll
    for (int a = 0; a < 4; a++)
        #pragma unroll
        for (int b = 0; b < 4; b++) accv[a][b] = zero;

    // staging: tile = 128 rows x 4 k-chunks of 16B. thread -> rows
    // {tid>>2, tid>>2+64}, k-chunk c = tid&3; swizzled col = c ^ ((r>>1)&3)
    // (rows r and r+64 share the same swizzle since (64>>1)&3 == 0).
    const int r0  = tid >> 2;
    const int c0  = tid & 3;
    const int cs  = c0 ^ ((r0 >> 1) & 3);
    const int lws = r0 * 32 + cs * 8;   // elem offset of chunk; row+64 at +2048
    const ushort* gA0 = Xb + (size_t)(rowA + r0) * DIM + c0 * 8;
    const ushort* gA1 = gA0 + (size_t)64 * DIM;
    const ushort* gB0 = Xb + (size_t)(rowB + r0) * DIM + c0 * 8;
    const ushort* gB1 = gB0 + (size_t)64 * DIM;

    // MFMA fragment offsets: A[m=lane&15][k=(lane>>4)*8+j]; the k-chunk this
    // lane wants is q=lane>>4, stored at swizzled column q ^ ((fr>>1)&3).
    const int fr = lane & 15;
    const int cc = (lane >> 4) ^ ((fr >> 1) & 3);
    const int fo = fr * 32 + cc * 8;    // frag elem offset within 16-row tile
    const int wr = (w & 1) * 64;
    const int wc = (w >> 1) * 64;

    // prologue: stage k0=0 through registers
    {
        uint4 pa0 = *(const uint4*)gA0;
        uint4 pa1 = *(const uint4*)gA1;
        uint4 pb0 = *(const uint4*)gB0;
        uint4 pb1 = *(const uint4*)gB1;
        *(uint4*)(As0 + lws)        = pa0;
        *(uint4*)(As0 + lws + 2048) = pa1;
        *(uint4*)(Bs0 + lws)        = pb0;
        *(uint4*)(Bs0 + lws + 2048) = pb1;
    }
    __syncthreads();

    ushort* curA = As0; ushort* nxtA = As1;
    ushort* curB = Bs0; ushort* nxtB = Bs1;

    #pragma unroll 1
    for (int k = 0; k < 16; k++) {
        // prefetch next K-slab into registers (pending during compute)
        uint4 pa0, pa1, pb0, pb1;
        const bool more = (k < 15);
        if (more) {
            const int k0 = (k + 1) * 32;
            pa0 = *(const uint4*)(gA0 + k0);
            pa1 = *(const uint4*)(gA1 + k0);
            pb0 = *(const uint4*)(gB0 + k0);
            pb1 = *(const uint4*)(gB1 + k0);
        }

        bf16x8 af[4], bfr[4];
        #pragma unroll
        for (int a = 0; a < 4; a++)
            af[a] = *(const bf16x8*)(curA + (wr + a * 16) * 32 + fo);
        #pragma unroll
        for (int b = 0; b < 4; b++)
            bfr[b] = *(const bf16x8*)(curB + (wc + b * 16) * 32 + fo);

        #pragma unroll
        for (int a = 0; a < 4; a++)
            #pragma unroll
            for (int b = 0; b < 4; b++)
                accv[a][b] = __builtin_amdgcn_mfma_f32_16x16x32_bf16(
                    af[a], bfr[b], accv[a][b], 0, 0, 0);

        if (more) {
            *(uint4*)(nxtA + lws)        = pa0;  // waits vmcnt for prefetch here
            *(uint4*)(nxtA + lws + 2048) = pa1;
            *(uint4*)(nxtB + lws)        = pb0;
            *(uint4*)(nxtB + lws + 2048) = pb1;
            __syncthreads();
            ushort* tA = curA; curA = nxtA; nxtA = tA;
            ushort* tB = curB; curB = nxtB; nxtB = tB;
        }
    }

    // epilogue: term = exp(-0.1*sqrt(max(ni+nj-2*dot, 0))); diag -> 1
    // C/D layout: col = lane&15, row = (lane>>4)*4 + reg
    const float wgt = (bi == bj) ? 1.0f : 2.0f;
    float lsum = 0.0f;
    #pragma unroll
    for (int a = 0; a < 4; a++) {
        const int gi0 = rowA + wr + a * 16 + (lane >> 4) * 4;
        #pragma unroll
        for (int b = 0; b < 4; b++) {
            const int gj = rowB + wc + b * 16 + (lane & 15);
            const float nj = norms[gj];
            #pragma unroll
            for (int r = 0; r < 4; r++) {
                const int gi = gi0 + r;
                float sq = fmaf(-2.0f, accv[a][b][r], norms[gi] + nj);
                sq = fmaxf(sq, 0.0f);
                float term = __expf(-0.1f * sqrtf(sq));
                if (gi == gj) term = 1.0f;
                lsum += term;
            }
        }
    }
    lsum *= wgt;
    #pragma unroll
    for (int off = 32; off > 0; off >>= 1) lsum += __shfl_down(lsum, off, 64);
    if (lane == 0) wsum[w] = lsum;
    __syncthreads();

    // block partial -> one device-scope atomic; last block finalizes output
    if (tid == 0) {
        atomicAdd(&acc[blockIdx.x & (NACC - 1)],
                  wsum[0] + wsum[1] + wsum[2] + wsum[3]);
        __threadfence();                       // release partials
        unsigned prev = atomicAdd(counter, 1u);
        is_last = (prev == NTRI - 1) ? 1 : 0;
    }
    __syncthreads();
    if (is_last) {
        __threadfence();                       // acquire all partials
        if (tid < 64) {
            float s = acc[tid];
            #pragma unroll
            for (int off = 32; off > 0; off >>= 1) s += __shfl_down(s, off, 64);
            if (tid == 0) {
                const float inv = 1.0f / ((float)NROWS * (float)NROWS);
                float loss = s * inv * 0.1f;
                out[0] = loss;
                out[1] = 0.5f * loss;
            }
        }
    }
}

extern "C" void kernel_launch(void* const* d_in, const int* in_sizes, int n_in,
                              void* d_out, int out_size, void* d_ws, size_t ws_size,
                              hipStream_t stream)
{
    const float* X = (const float*)d_in[0];
    float* out = (float*)d_out;

    char* ws = (char*)d_ws;
    float*    acc     = (float*)ws;                   // NACC fp32 slots
    unsigned* counter = (unsigned*)(ws + 512);        // done-block counter
    float*    norms   = (float*)(ws + 1024);          // 8192 fp32 (32 KB)
    ushort*   Xb      = (ushort*)(ws + 1024 + 32768); // bf16 X, 8 MB

    norm_convert_kernel<<<NROWS / 4, 256, 0, stream>>>(X, Xb, norms, acc, counter);
    pair_loss_gemm_kernel<<<NTRI, 256, 0, stream>>>(Xb, norms, acc, counter, out);
}

// Round 4
// 154.773 us; speedup vs baseline: 1.0098x; 1.0098x over previous
//
#include <hip/hip_runtime.h>

// Problem constants
#define NROWS 8192   // 4 * 2048
#define DIM   512
#define NT    64                    // 8192 / 128 tiles per side
#define NTRI  (NT * (NT + 1) / 2)   // 2080 upper-triangular tile blocks
#define NACC  64                    // accumulator slots (contention spread)

using bf16x8 = __attribute__((ext_vector_type(8))) __bf16;
using f32x4  = __attribute__((ext_vector_type(4))) float;

// round-to-nearest-even fp32 -> bf16 bits
__device__ __forceinline__ ushort f2bf(float f) {
    unsigned u = __float_as_uint(f);
    unsigned r = u + 0x7fffu + ((u >> 16) & 1u);
    return (ushort)(r >> 16);
}

// Kernel 1: fp32 row norms + fp32->bf16 conversion; zeroes acc slots.
// One wave per row (512 elems = 64 lanes x 8).
__global__ __launch_bounds__(256) void norm_convert_kernel(
    const float* __restrict__ X, ushort* __restrict__ Xb,
    float* __restrict__ norms, float* __restrict__ acc)
{
    const int tid  = threadIdx.x;
    const int lane = tid & 63;
    const int w    = tid >> 6;
    const int row  = blockIdx.x * 4 + w;

    if (blockIdx.x == 0 && tid < NACC) acc[tid] = 0.0f;

    const float* xr = X + (size_t)row * DIM + lane * 8;
    float4 v0 = *(const float4*)xr;
    float4 v1 = *(const float4*)(xr + 4);

    float s = 0.0f;
    s = fmaf(v0.x, v0.x, s); s = fmaf(v0.y, v0.y, s);
    s = fmaf(v0.z, v0.z, s); s = fmaf(v0.w, v0.w, s);
    s = fmaf(v1.x, v1.x, s); s = fmaf(v1.y, v1.y, s);
    s = fmaf(v1.z, v1.z, s); s = fmaf(v1.w, v1.w, s);

    union { ushort u16[8]; uint4 v; } pk;
    pk.u16[0] = f2bf(v0.x); pk.u16[1] = f2bf(v0.y);
    pk.u16[2] = f2bf(v0.z); pk.u16[3] = f2bf(v0.w);
    pk.u16[4] = f2bf(v1.x); pk.u16[5] = f2bf(v1.y);
    pk.u16[6] = f2bf(v1.z); pk.u16[7] = f2bf(v1.w);
    *(uint4*)(Xb + (size_t)row * DIM + lane * 8) = pk.v;

    #pragma unroll
    for (int off = 32; off > 0; off >>= 1) s += __shfl_down(s, off, 64);
    if (lane == 0) norms[row] = s;
}

// Kernel 2: upper-triangular tiled X·X^T (bf16 MFMA) + fused sqrt/exp/sum
// epilogue. 128x128 tile/block, 4 waves, 64x64 quadrant/wave, BK=32.
//
// 2-deep register-prefetch pipeline: loads for slab k+2 are issued at the
// top of iter k (into reg set P or Q alternating) and consumed by ds_write
// at the END of iter k+1 -> ~2 compute iterations of latency budget, no
// vmcnt(0) drain of in-flight prefetches at the barrier.
//
// LDS layout: XOR-swizzled (16B chunk c of row r stored at column
// c ^ ((r>>1)&3)) -> conflict-free reads and writes, 32KB total.
//
// NO device-scope fences here: an agent fence on gfx950 = whole per-XCD L2
// writeback+invalidate (non-coherent L2s) -> nukes Xb residency. Round-3
// measured: per-block __threadfence cost 62->104us. Finalize is a separate
// kernel instead.
__global__ __launch_bounds__(256, 4) void pair_loss_gemm_kernel(
    const ushort* __restrict__ Xb, const float* __restrict__ norms,
    float* __restrict__ acc)
{
    __shared__ __align__(16) ushort As0[128 * 32];
    __shared__ __align__(16) ushort As1[128 * 32];
    __shared__ __align__(16) ushort Bs0[128 * 32];
    __shared__ __align__(16) ushort Bs1[128 * 32];
    __shared__ float wsum[4];

    // decode linear block id -> upper-triangular (bi, bj), bi <= bj
    int t = blockIdx.x, bi = 0;
    while (t >= (NT - bi)) { t -= (NT - bi); bi++; }
    const int bj = bi + t;

    const int tid  = threadIdx.x;
    const int lane = tid & 63;
    const int w    = tid >> 6;

    const int rowA = bi * 128;
    const int rowB = bj * 128;

    f32x4 accv[4][4];
    const f32x4 zero = {0.0f, 0.0f, 0.0f, 0.0f};
    #pragma unroll
    for (int a = 0; a < 4; a++)
        #pragma unroll
        for (int b = 0; b < 4; b++) accv[a][b] = zero;

    // staging: thread -> rows {tid>>2, tid>>2+64}, k-chunk c = tid&3;
    // swizzled col = c ^ ((r>>1)&3); rows r,r+64 share swizzle.
    const int r0  = tid >> 2;
    const int c0  = tid & 3;
    const int cs  = c0 ^ ((r0 >> 1) & 3);
    const int lws = r0 * 32 + cs * 8;   // elem offset; row+64 chunk at +2048
    const ushort* gA0 = Xb + (size_t)(rowA + r0) * DIM + c0 * 8;
    const ushort* gA1 = gA0 + (size_t)64 * DIM;
    const ushort* gB0 = Xb + (size_t)(rowB + r0) * DIM + c0 * 8;
    const ushort* gB1 = gB0 + (size_t)64 * DIM;

    // MFMA fragment: A[m=lane&15][k=(lane>>4)*8+j]; lane's k-chunk q=lane>>4
    // lives at swizzled column q ^ ((fr>>1)&3).
    const int fr = lane & 15;
    const int cc = (lane >> 4) ^ ((fr >> 1) & 3);
    const int fo = fr * 32 + cc * 8;
    const int wr = (w & 1) * 64;
    const int wc = (w >> 1) * 64;

    uint4 Pa0, Pa1, Pb0, Pb1;   // reg set P
    uint4 Qa0, Qa1, Qb0, Qb1;   // reg set Q

    // prologue: slab0 -> LDS0 (through P), then slab1 -> P
    Pa0 = *(const uint4*)gA0;  Pa1 = *(const uint4*)gA1;
    Pb0 = *(const uint4*)gB0;  Pb1 = *(const uint4*)gB1;
    *(uint4*)(As0 + lws)        = Pa0;
    *(uint4*)(As0 + lws + 2048) = Pa1;
    *(uint4*)(Bs0 + lws)        = Pb0;
    *(uint4*)(Bs0 + lws + 2048) = Pb1;
    Pa0 = *(const uint4*)(gA0 + 32);  Pa1 = *(const uint4*)(gA1 + 32);
    Pb0 = *(const uint4*)(gB0 + 32);  Pb1 = *(const uint4*)(gB1 + 32);
    __syncthreads();

    #pragma unroll 1
    for (int k = 0; k < 16; k += 2) {
        // ---- even iter k: compute from LDS0, write slab k+1 (P) -> LDS1 ----
        if (k + 2 < 16) {
            const int k0 = (k + 2) * 32;
            Qa0 = *(const uint4*)(gA0 + k0);  Qa1 = *(const uint4*)(gA1 + k0);
            Qb0 = *(const uint4*)(gB0 + k0);  Qb1 = *(const uint4*)(gB1 + k0);
        }
        {
            bf16x8 af[4], bfr[4];
            #pragma unroll
            for (int a = 0; a < 4; a++)
                af[a] = *(const bf16x8*)(As0 + (wr + a * 16) * 32 + fo);
            #pragma unroll
            for (int b = 0; b < 4; b++)
                bfr[b] = *(const bf16x8*)(Bs0 + (wc + b * 16) * 32 + fo);
            #pragma unroll
            for (int a = 0; a < 4; a++)
                #pragma unroll
                for (int b = 0; b < 4; b++)
                    accv[a][b] = __builtin_amdgcn_mfma_f32_16x16x32_bf16(
                        af[a], bfr[b], accv[a][b], 0, 0, 0);
        }
        *(uint4*)(As1 + lws)        = Pa0;
        *(uint4*)(As1 + lws + 2048) = Pa1;
        *(uint4*)(Bs1 + lws)        = Pb0;
        *(uint4*)(Bs1 + lws + 2048) = Pb1;
        __syncthreads();

        // ---- odd iter k+1: compute from LDS1, write slab k+2 (Q) -> LDS0 ----
        if (k + 3 < 16) {
            const int k0 = (k + 3) * 32;
            Pa0 = *(const uint4*)(gA0 + k0);  Pa1 = *(const uint4*)(gA1 + k0);
            Pb0 = *(const uint4*)(gB0 + k0);  Pb1 = *(const uint4*)(gB1 + k0);
        }
        {
            bf16x8 af[4], bfr[4];
            #pragma unroll
            for (int a = 0; a < 4; a++)
                af[a] = *(const bf16x8*)(As1 + (wr + a * 16) * 32 + fo);
            #pragma unroll
            for (int b = 0; b < 4; b++)
                bfr[b] = *(const bf16x8*)(Bs1 + (wc + b * 16) * 32 + fo);
            #pragma unroll
            for (int a = 0; a < 4; a++)
                #pragma unroll
                for (int b = 0; b < 4; b++)
                    accv[a][b] = __builtin_amdgcn_mfma_f32_16x16x32_bf16(
                        af[a], bfr[b], accv[a][b], 0, 0, 0);
        }
        if (k + 2 < 16) {
            *(uint4*)(As0 + lws)        = Qa0;
            *(uint4*)(As0 + lws + 2048) = Qa1;
            *(uint4*)(Bs0 + lws)        = Qb0;
            *(uint4*)(Bs0 + lws + 2048) = Qb1;
            __syncthreads();
        }
    }

    // epilogue: term = exp(-0.1*sqrt(max(ni+nj-2*dot, 0))); diag -> 1
    // C/D layout: col = lane&15, row = (lane>>4)*4 + reg
    const float wgt = (bi == bj) ? 1.0f : 2.0f;
    float lsum = 0.0f;
    #pragma unroll
    for (int a = 0; a < 4; a++) {
        const int gi0 = rowA + wr + a * 16 + (lane >> 4) * 4;
        #pragma unroll
        for (int b = 0; b < 4; b++) {
            const int gj = rowB + wc + b * 16 + (lane & 15);
            const float nj = norms[gj];
            #pragma unroll
            for (int r = 0; r < 4; r++) {
                const int gi = gi0 + r;
                float sq = fmaf(-2.0f, accv[a][b][r], norms[gi] + nj);
                sq = fmaxf(sq, 0.0f);
                float term = __expf(-0.1f * sqrtf(sq));
                if (gi == gj) term = 1.0f;
                lsum += term;
            }
        }
    }
    lsum *= wgt;
    #pragma unroll
    for (int off = 32; off > 0; off >>= 1) lsum += __shfl_down(lsum, off, 64);
    if (lane == 0) wsum[w] = lsum;
    __syncthreads();
    if (tid == 0)
        atomicAdd(&acc[blockIdx.x & (NACC - 1)],
                  wsum[0] + wsum[1] + wsum[2] + wsum[3]);
}

// Kernel 3: finalize scalar outputs (sum NACC slots)
__global__ void finalize_kernel(const float* __restrict__ acc,
                                float* __restrict__ out)
{
    const int lane = threadIdx.x;
    float s = (lane < NACC) ? acc[lane] : 0.0f;
    #pragma unroll
    for (int off = 32; off > 0; off >>= 1) s += __shfl_down(s, off, 64);
    if (lane == 0) {
        const float inv = 1.0f / ((float)NROWS * (float)NROWS); // 2^-26 exact
        float loss = s * inv * 0.1f;
        out[0] = loss;
        out[1] = 0.5f * loss;
    }
}

extern "C" void kernel_launch(void* const* d_in, const int* in_sizes, int n_in,
                              void* d_out, int out_size, void* d_ws, size_t ws_size,
                              hipStream_t stream)
{
    const float* X = (const float*)d_in[0];
    float* out = (float*)d_out;

    char* ws = (char*)d_ws;
    float*  acc   = (float*)ws;                   // NACC fp32 slots
    float*  norms = (float*)(ws + 1024);          // 8192 fp32 (32 KB)
    ushort* Xb    = (ushort*)(ws + 1024 + 32768); // bf16 X, 8 MB

    norm_convert_kernel<<<NROWS / 4, 256, 0, stream>>>(X, Xb, norms, acc);
    pair_loss_gemm_kernel<<<NTRI, 256, 0, stream>>>(Xb, norms, acc);
    finalize_kernel<<<1, 64, 0, stream>>>(acc, out);
}

// Round 5
// 119.799 us; speedup vs baseline: 1.3046x; 1.2919x over previous
//
#include <hip/hip_runtime.h>

// Problem constants
#define NROWS 8192   // 4 * 2048
#define DIM   512
#define NT    64                    // 8192 / 128 tiles per side
#define NTRI  (NT * (NT + 1) / 2)   // 2080 upper-triangular tile blocks
#define NACC  64                    // accumulator slots (contention spread)

using bf16x8 = __attribute__((ext_vector_type(8))) __bf16;
using f32x4  = __attribute__((ext_vector_type(4))) float;

// round-to-nearest-even fp32 -> bf16 bits
__device__ __forceinline__ ushort f2bf(float f) {
    unsigned u = __float_as_uint(f);
    unsigned r = u + 0x7fffu + ((u >> 16) & 1u);
    return (ushort)(r >> 16);
}

// Kernel 1: fp32 row norms + fp32->bf16 conversion; zeroes acc slots.
// One wave per row (512 elems = 64 lanes x 8).
__global__ __launch_bounds__(256) void norm_convert_kernel(
    const float* __restrict__ X, ushort* __restrict__ Xb,
    float* __restrict__ norms, float* __restrict__ acc)
{
    const int tid  = threadIdx.x;
    const int lane = tid & 63;
    const int w    = tid >> 6;
    const int row  = blockIdx.x * 4 + w;

    if (blockIdx.x == 0 && tid < NACC) acc[tid] = 0.0f;

    const float* xr = X + (size_t)row * DIM + lane * 8;
    float4 v0 = *(const float4*)xr;
    float4 v1 = *(const float4*)(xr + 4);

    float s = 0.0f;
    s = fmaf(v0.x, v0.x, s); s = fmaf(v0.y, v0.y, s);
    s = fmaf(v0.z, v0.z, s); s = fmaf(v0.w, v0.w, s);
    s = fmaf(v1.x, v1.x, s); s = fmaf(v1.y, v1.y, s);
    s = fmaf(v1.z, v1.z, s); s = fmaf(v1.w, v1.w, s);

    union { ushort u16[8]; uint4 v; } pk;
    pk.u16[0] = f2bf(v0.x); pk.u16[1] = f2bf(v0.y);
    pk.u16[2] = f2bf(v0.z); pk.u16[3] = f2bf(v0.w);
    pk.u16[4] = f2bf(v1.x); pk.u16[5] = f2bf(v1.y);
    pk.u16[6] = f2bf(v1.z); pk.u16[7] = f2bf(v1.w);
    *(uint4*)(Xb + (size_t)row * DIM + lane * 8) = pk.v;

    #pragma unroll
    for (int off = 32; off > 0; off >>= 1) s += __shfl_down(s, off, 64);
    if (lane == 0) norms[row] = s;
}

// Kernel 2: upper-triangular tiled X·X^T (bf16 MFMA) + fused sqrt/exp/sum
// epilogue. 128x128 tile/block, 4 waves, 64x64 quadrant/wave, BK=32.
//
// 1-deep register-prefetch pipeline (round-2 structure, the verified one):
//   top of iter k: global loads slab k+1 -> VGPRs (4 uint4 = 16 regs)
//   middle:        ds_read frags from cur buf, 16 MFMAs
//   bottom:        ds_write prefetch regs -> next buf, ONE barrier/iter
// Register budget at __launch_bounds__(256,4) is 128 unified VGPR+AGPR:
// 64 acc + 16 prefetch + ~44 frags/addr = ~124. A 2-deep pipeline (2 reg
// sets) does NOT fit -> spills -> 160 MB scratch writebacks, 100 us
// (round-4 measured). Do not deepen without shrinking the accumulator.
//
// LDS layout: XOR-swizzled (16B chunk c of row r stored at column
// c ^ ((r>>1)&3)) -> conflict-free reads and writes (round 3/4: 4.26M -> 0),
// 32KB total so LDS still allows 4 blocks/CU.
//
// NO device-scope fences: agent fence = per-XCD L2 writeback+invalidate
// (round-3 measured: 62->104 us). Finalize is a separate tiny kernel.
__global__ __launch_bounds__(256, 4) void pair_loss_gemm_kernel(
    const ushort* __restrict__ Xb, const float* __restrict__ norms,
    float* __restrict__ acc)
{
    __shared__ __align__(16) ushort As0[128 * 32];
    __shared__ __align__(16) ushort As1[128 * 32];
    __shared__ __align__(16) ushort Bs0[128 * 32];
    __shared__ __align__(16) ushort Bs1[128 * 32];
    __shared__ float wsum[4];

    // decode linear block id -> upper-triangular (bi, bj), bi <= bj
    int t = blockIdx.x, bi = 0;
    while (t >= (NT - bi)) { t -= (NT - bi); bi++; }
    const int bj = bi + t;

    const int tid  = threadIdx.x;
    const int lane = tid & 63;
    const int w    = tid >> 6;

    const int rowA = bi * 128;
    const int rowB = bj * 128;

    f32x4 accv[4][4];
    const f32x4 zero = {0.0f, 0.0f, 0.0f, 0.0f};
    #pragma unroll
    for (int a = 0; a < 4; a++)
        #pragma unroll
        for (int b = 0; b < 4; b++) accv[a][b] = zero;

    // staging: thread -> rows {tid>>2, tid>>2+64}, k-chunk c = tid&3;
    // swizzled col = c ^ ((r>>1)&3); rows r and r+64 share the swizzle.
    const int r0  = tid >> 2;
    const int c0  = tid & 3;
    const int cs  = c0 ^ ((r0 >> 1) & 3);
    const int lws = r0 * 32 + cs * 8;   // elem offset; row+64 chunk at +2048
    const ushort* gA0 = Xb + (size_t)(rowA + r0) * DIM + c0 * 8;
    const ushort* gA1 = gA0 + (size_t)64 * DIM;
    const ushort* gB0 = Xb + (size_t)(rowB + r0) * DIM + c0 * 8;
    const ushort* gB1 = gB0 + (size_t)64 * DIM;

    // MFMA fragment: A[m=lane&15][k=(lane>>4)*8+j]; lane's k-chunk q=lane>>4
    // lives at swizzled column q ^ ((fr>>1)&3).
    const int fr = lane & 15;
    const int cc = (lane >> 4) ^ ((fr >> 1) & 3);
    const int fo = fr * 32 + cc * 8;
    const int wr = (w & 1) * 64;
    const int wc = (w >> 1) * 64;

    // prologue: stage slab 0 through registers
    {
        uint4 pa0 = *(const uint4*)gA0;
        uint4 pa1 = *(const uint4*)gA1;
        uint4 pb0 = *(const uint4*)gB0;
        uint4 pb1 = *(const uint4*)gB1;
        *(uint4*)(As0 + lws)        = pa0;
        *(uint4*)(As0 + lws + 2048) = pa1;
        *(uint4*)(Bs0 + lws)        = pb0;
        *(uint4*)(Bs0 + lws + 2048) = pb1;
    }
    __syncthreads();

    ushort* curA = As0; ushort* nxtA = As1;
    ushort* curB = Bs0; ushort* nxtB = Bs1;

    #pragma unroll 1
    for (int k = 0; k < 16; k++) {
        // prefetch next K-slab into registers (in flight during compute)
        uint4 pa0, pa1, pb0, pb1;
        const bool more = (k < 15);
        if (more) {
            const int k0 = (k + 1) * 32;
            pa0 = *(const uint4*)(gA0 + k0);
            pa1 = *(const uint4*)(gA1 + k0);
            pb0 = *(const uint4*)(gB0 + k0);
            pb1 = *(const uint4*)(gB1 + k0);
        }

        bf16x8 af[4], bfr[4];
        #pragma unroll
        for (int a = 0; a < 4; a++)
            af[a] = *(const bf16x8*)(curA + (wr + a * 16) * 32 + fo);
        #pragma unroll
        for (int b = 0; b < 4; b++)
            bfr[b] = *(const bf16x8*)(curB + (wc + b * 16) * 32 + fo);

        #pragma unroll
        for (int a = 0; a < 4; a++)
            #pragma unroll
            for (int b = 0; b < 4; b++)
                accv[a][b] = __builtin_amdgcn_mfma_f32_16x16x32_bf16(
                    af[a], bfr[b], accv[a][b], 0, 0, 0);

        if (more) {
            *(uint4*)(nxtA + lws)        = pa0;  // vmcnt wait lands here
            *(uint4*)(nxtA + lws + 2048) = pa1;
            *(uint4*)(nxtB + lws)        = pb0;
            *(uint4*)(nxtB + lws + 2048) = pb1;
            __syncthreads();
            ushort* tA = curA; curA = nxtA; nxtA = tA;
            ushort* tB = curB; curB = nxtB; nxtB = tB;
        }
    }

    // epilogue: term = exp(-0.1*sqrt(max(ni+nj-2*dot, 0))); diag -> 1
    // C/D layout: col = lane&15, row = (lane>>4)*4 + reg
    const float wgt = (bi == bj) ? 1.0f : 2.0f;
    float lsum = 0.0f;
    #pragma unroll
    for (int a = 0; a < 4; a++) {
        const int gi0 = rowA + wr + a * 16 + (lane >> 4) * 4;
        #pragma unroll
        for (int b = 0; b < 4; b++) {
            const int gj = rowB + wc + b * 16 + (lane & 15);
            const float nj = norms[gj];
            #pragma unroll
            for (int r = 0; r < 4; r++) {
                const int gi = gi0 + r;
                float sq = fmaf(-2.0f, accv[a][b][r], norms[gi] + nj);
                sq = fmaxf(sq, 0.0f);
                float term = __expf(-0.1f * sqrtf(sq));
                if (gi == gj) term = 1.0f;
                lsum += term;
            }
        }
    }
    lsum *= wgt;
    #pragma unroll
    for (int off = 32; off > 0; off >>= 1) lsum += __shfl_down(lsum, off, 64);
    if (lane == 0) wsum[w] = lsum;
    __syncthreads();
    if (tid == 0)
        atomicAdd(&acc[blockIdx.x & (NACC - 1)],
                  wsum[0] + wsum[1] + wsum[2] + wsum[3]);
}

// Kernel 3: finalize scalar outputs (sum NACC slots)
__global__ void finalize_kernel(const float* __restrict__ acc,
                                float* __restrict__ out)
{
    const int lane = threadIdx.x;
    float s = (lane < NACC) ? acc[lane] : 0.0f;
    #pragma unroll
    for (int off = 32; off > 0; off >>= 1) s += __shfl_down(s, off, 64);
    if (lane == 0) {
        const float inv = 1.0f / ((float)NROWS * (float)NROWS); // 2^-26 exact
        float loss = s * inv * 0.1f;
        out[0] = loss;
        out[1] = 0.5f * loss;
    }
}

extern "C" void kernel_launch(void* const* d_in, const int* in_sizes, int n_in,
                              void* d_out, int out_size, void* d_ws, size_t ws_size,
                              hipStream_t stream)
{
    const float* X = (const float*)d_in[0];
    float* out = (float*)d_out;

    char* ws = (char*)d_ws;
    float*  acc   = (float*)ws;                   // NACC fp32 slots
    float*  norms = (float*)(ws + 1024);          // 8192 fp32 (32 KB)
    ushort* Xb    = (ushort*)(ws + 1024 + 32768); // bf16 X, 8 MB

    norm_convert_kernel<<<NROWS / 4, 256, 0, stream>>>(X, Xb, norms, acc);
    pair_loss_gemm_kernel<<<NTRI, 256, 0, stream>>>(Xb, norms, acc);
    finalize_kernel<<<1, 64, 0, stream>>>(acc, out);
}

// Round 7
// 116.483 us; speedup vs baseline: 1.3418x; 1.0285x over previous
//
#include <hip/hip_runtime.h>

// Problem constants
#define NROWS 8192   // 4 * 2048
#define DIM   512
#define NT    64                    // 8192 / 128 tiles per side
#define NTRI  (NT * (NT + 1) / 2)   // 2080 upper-triangular tile blocks
#define NACC  64                    // accumulator slots (contention spread)

using f32x4 = __attribute__((ext_vector_type(4))) float;

// Software fp32 -> OCP e4m3fn, round-to-nearest-even. No fp8 cvt builtins
// (round-6 crash suspect). Verified edges: 0, denormal grid (step 2^-9,
// RNE ties-to-even via rintf), binade promote (e.g. 447->448), clamp 448.
__device__ __forceinline__ unsigned char f2e4m3(float x) {
    unsigned ux = __float_as_uint(x);
    unsigned s  = (ux >> 24) & 0x80u;
    float a = __uint_as_float(ux & 0x7FFFFFFFu);     // |x|, finite for our data
    a = fminf(a, 448.0f);                            // clamp to max finite
    unsigned ua = __float_as_uint(a);
    int eb = (int)(ua >> 23);                        // biased exponent
    if (eb < 121) eb = 121;                          // denormal region: step 2^-9
    float step = __uint_as_float((unsigned)(eb - 3) << 23);   // 2^(eb-127-3)
    float q = rintf(a / step) * step;                // RNE on e4m3 grid (ratio<=16)
    q = fminf(q, 448.0f);
    if (q < 0.001953125f)                            // below min denormal 2^-9 -> 0
        return (unsigned char)s;
    unsigned uq = __float_as_uint(q);
    int eq = (int)(uq >> 23) - 127;
    unsigned byte;
    if (eq < -6) byte = (unsigned)(q * 512.0f);      // denormal: d*2^-9, d in 1..7
    else         byte = (unsigned)((eq + 7) << 3) | ((uq >> 20) & 7u);
    return (unsigned char)(s | byte);
}

// Kernel 1: fp32 row norms + fp32->fp8(e4m3) conversion; zeroes acc slots.
// One wave per row (512 elems = 64 lanes x 8). Norms stay fp32-exact, so fp8
// error enters only through the dot product (zero-mean, ~0.2%/term vs 2% tol).
__global__ __launch_bounds__(256) void norm_convert_kernel(
    const float* __restrict__ X, unsigned char* __restrict__ Xq,
    float* __restrict__ norms, float* __restrict__ acc)
{
    const int tid  = threadIdx.x;
    const int lane = tid & 63;
    const int w    = tid >> 6;
    const int row  = blockIdx.x * 4 + w;

    if (blockIdx.x == 0 && tid < NACC) acc[tid] = 0.0f;

    const float* xr = X + (size_t)row * DIM + lane * 8;
    float4 v0 = *(const float4*)xr;
    float4 v1 = *(const float4*)(xr + 4);

    float s = 0.0f;
    s = fmaf(v0.x, v0.x, s); s = fmaf(v0.y, v0.y, s);
    s = fmaf(v0.z, v0.z, s); s = fmaf(v0.w, v0.w, s);
    s = fmaf(v1.x, v1.x, s); s = fmaf(v1.y, v1.y, s);
    s = fmaf(v1.z, v1.z, s); s = fmaf(v1.w, v1.w, s);

    union { unsigned char b[8]; uint2 v; } pk;
    pk.b[0] = f2e4m3(v0.x); pk.b[1] = f2e4m3(v0.y);
    pk.b[2] = f2e4m3(v0.z); pk.b[3] = f2e4m3(v0.w);
    pk.b[4] = f2e4m3(v1.x); pk.b[5] = f2e4m3(v1.y);
    pk.b[6] = f2e4m3(v1.z); pk.b[7] = f2e4m3(v1.w);
    *(uint2*)(Xq + (size_t)row * DIM + lane * 8) = pk.v;

    #pragma unroll
    for (int off = 32; off > 0; off >>= 1) s += __shfl_down(s, off, 64);
    if (lane == 0) norms[row] = s;
}

// Kernel 2: upper-triangular tiled X·X^T (fp8 e4m3 MFMA, runs at bf16 rate)
// + fused sqrt/exp/sum epilogue. 128x128 tile/block, 4 waves, 64x64
// quadrant/wave, BK=32 via 16x16x32_fp8_fp8.
//
// fp8 halves every pressured pipe vs bf16 (round-5: LDS demand ~7x MFMA):
// frag reads ds_read_b64, staging 16B/thread/iter per matrix, prefetch 8
// VGPRs, and Xq = 4MB fits in each XCD's 4MB L2.
//
// 1-deep register-prefetch pipeline (verified; 2-deep spills at the 128-reg
// budget -> 160MB scratch, round-4 measured).
// LDS layout per tile: K-major halves, off(r,h) = h*2048 + r*16 -> b64
// reads and b128 writes both <=2-way (free, m136).
// NO device-scope fences (round-3: agent fence = per-XCD L2 flush, +40us).
__global__ __launch_bounds__(256, 4) void pair_loss_gemm_kernel(
    const unsigned char* __restrict__ Xq, const float* __restrict__ norms,
    float* __restrict__ acc)
{
    __shared__ __align__(16) char As0[4096];
    __shared__ __align__(16) char As1[4096];
    __shared__ __align__(16) char Bs0[4096];
    __shared__ __align__(16) char Bs1[4096];
    __shared__ float wsum[4];

    // decode linear block id -> upper-triangular (bi, bj), bi <= bj
    int t = blockIdx.x, bi = 0;
    while (t >= (NT - bi)) { t -= (NT - bi); bi++; }
    const int bj = bi + t;

    const int tid  = threadIdx.x;
    const int lane = tid & 63;
    const int w    = tid >> 6;

    const int rowA = bi * 128;
    const int rowB = bj * 128;

    f32x4 accv[4][4];
    const f32x4 zero = {0.0f, 0.0f, 0.0f, 0.0f};
    #pragma unroll
    for (int a = 0; a < 4; a++)
        #pragma unroll
        for (int b = 0; b < 4; b++) accv[a][b] = zero;

    // staging: thread -> row r = tid>>1 (0..127), 16B-half h = tid&1.
    const int r0 = tid >> 1;
    const int h0 = tid & 1;
    const int wb = h0 * 2048 + r0 * 16;          // LDS byte offset
    const unsigned char* gA = Xq + (size_t)(rowA + r0) * DIM + h0 * 16;
    const unsigned char* gB = Xq + (size_t)(rowB + r0) * DIM + h0 * 16;

    // MFMA fp8 frag: lane holds A[m=lane&15][k=q*8..q*8+7], q=lane>>4 (8B).
    // K-major layout: byte addr = (q>>1)*2048 + row*16 + (q&1)*8.
    const int fr = lane & 15;
    const int q  = lane >> 4;
    const int fo = (q >> 1) * 2048 + fr * 16 + (q & 1) * 8;
    const int wr = (w & 1) * 64;
    const int wc = (w >> 1) * 64;

    // prologue: stage slab 0 through registers
    {
        uint4 pa = *(const uint4*)gA;
        uint4 pb = *(const uint4*)gB;
        *(uint4*)(As0 + wb) = pa;
        *(uint4*)(Bs0 + wb) = pb;
    }
    __syncthreads();

    char* curA = As0; char* nxtA = As1;
    char* curB = Bs0; char* nxtB = Bs1;

    #pragma unroll 1
    for (int k = 0; k < 16; k++) {
        // prefetch next 32-byte K-slab into registers (in flight during MFMA)
        uint4 pa, pb;
        const bool more = (k < 15);
        if (more) {
            const int k0 = (k + 1) * 32;
            pa = *(const uint4*)(gA + k0);
            pb = *(const uint4*)(gB + k0);
        }

        long af[4], bf[4];
        #pragma unroll
        for (int a = 0; a < 4; a++)
            af[a] = *(const long*)(curA + (wr + a * 16) * 16 + fo);
        #pragma unroll
        for (int b = 0; b < 4; b++)
            bf[b] = *(const long*)(curB + (wc + b * 16) * 16 + fo);

        #pragma unroll
        for (int a = 0; a < 4; a++)
            #pragma unroll
            for (int b = 0; b < 4; b++)
                accv[a][b] = __builtin_amdgcn_mfma_f32_16x16x32_fp8_fp8(
                    af[a], bf[b], accv[a][b], 0, 0, 0);

        if (more) {
            *(uint4*)(nxtA + wb) = pa;   // vmcnt wait lands here, not barrier
            *(uint4*)(nxtB + wb) = pb;
            __syncthreads();
            char* tA = curA; curA = nxtA; nxtA = tA;
            char* tB = curB; curB = nxtB; nxtB = tB;
        }
    }

    // epilogue: term = exp(-0.1*sqrt(max(ni+nj-2*dot, 0))); diag -> 1
    // C/D layout: col = lane&15, row = (lane>>4)*4 + reg (dtype-independent)
    const float wgt = (bi == bj) ? 1.0f : 2.0f;
    float lsum = 0.0f;
    #pragma unroll
    for (int a = 0; a < 4; a++) {
        const int gi0 = rowA + wr + a * 16 + (lane >> 4) * 4;
        #pragma unroll
        for (int b = 0; b < 4; b++) {
            const int gj = rowB + wc + b * 16 + (lane & 15);
            const float nj = norms[gj];
            #pragma unroll
            for (int r = 0; r < 4; r++) {
                const int gi = gi0 + r;
                float sq = fmaf(-2.0f, accv[a][b][r], norms[gi] + nj);
                sq = fmaxf(sq, 0.0f);
                float term = __expf(-0.1f * sqrtf(sq));
                if (gi == gj) term = 1.0f;
                lsum += term;
            }
        }
    }
    lsum *= wgt;
    #pragma unroll
    for (int off = 32; off > 0; off >>= 1) lsum += __shfl_down(lsum, off, 64);
    if (lane == 0) wsum[w] = lsum;
    __syncthreads();
    if (tid == 0)
        atomicAdd(&acc[blockIdx.x & (NACC - 1)],
                  wsum[0] + wsum[1] + wsum[2] + wsum[3]);
}

// Kernel 3: finalize scalar outputs (sum NACC slots)
__global__ void finalize_kernel(const float* __restrict__ acc,
                                float* __restrict__ out)
{
    const int lane = threadIdx.x;
    float s = (lane < NACC) ? acc[lane] : 0.0f;
    #pragma unroll
    for (int off = 32; off > 0; off >>= 1) s += __shfl_down(s, off, 64);
    if (lane == 0) {
        const float inv = 1.0f / ((float)NROWS * (float)NROWS); // 2^-26 exact
        float loss = s * inv * 0.1f;
        out[0] = loss;
        out[1] = 0.5f * loss;
    }
}

extern "C" void kernel_launch(void* const* d_in, const int* in_sizes, int n_in,
                              void* d_out, int out_size, void* d_ws, size_t ws_size,
                              hipStream_t stream)
{
    const float* X = (const float*)d_in[0];
    float* out = (float*)d_out;

    char* ws = (char*)d_ws;
    float*         acc   = (float*)ws;                   // NACC fp32 slots
    float*         norms = (float*)(ws + 1024);          // 8192 fp32 (32 KB)
    unsigned char* Xq    = (unsigned char*)(ws + 1024 + 32768); // fp8 X, 4 MB

    norm_convert_kernel<<<NROWS / 4, 256, 0, stream>>>(X, Xq, norms, acc);
    pair_loss_gemm_kernel<<<NTRI, 256, 0, stream>>>(Xq, norms, acc);
    finalize_kernel<<<1, 64, 0, stream>>>(acc, out);
}

// Round 8
// 114.383 us; speedup vs baseline: 1.3664x; 1.0184x over previous
//
#include <hip/hip_runtime.h>

// Problem constants
#define NROWS 8192   // 4 * 2048
#define DIM   512
#define NT    64                    // 8192 / 128 tiles per side
#define NTRI  (NT * (NT + 1) / 2)   // 2080 upper-triangular tile blocks
#define NACC  64                    // accumulator slots (contention spread)

using f32x4 = __attribute__((ext_vector_type(4))) float;

// Software fp32 -> OCP e4m3fn, round-to-nearest-even. (fp8 cvt builtin was
// the round-6 crash suspect; SW encoder verified r7.) Division replaced by
// exact power-of-2 reciprocal multiply.
__device__ __forceinline__ unsigned char f2e4m3(float x) {
    unsigned ux = __float_as_uint(x);
    unsigned s  = (ux >> 24) & 0x80u;
    float a = __uint_as_float(ux & 0x7FFFFFFFu);     // |x|, finite for our data
    a = fminf(a, 448.0f);                            // clamp to max finite
    unsigned ua = __float_as_uint(a);
    int eb = (int)(ua >> 23);                        // biased exponent
    if (eb < 121) eb = 121;                          // denormal region: step 2^-9
    float step  = __uint_as_float((unsigned)(eb - 3) << 23);    // 2^(eb-130)
    float istep = __uint_as_float((unsigned)(257 - eb) << 23);  // 2^(130-eb), exact
    float q = rintf(a * istep) * step;               // RNE on e4m3 grid
    q = fminf(q, 448.0f);
    if (q < 0.001953125f)                            // below min denormal 2^-9 -> 0
        return (unsigned char)s;
    unsigned uq = __float_as_uint(q);
    int eq = (int)(uq >> 23) - 127;
    unsigned byte;
    if (eq < -6) byte = (unsigned)(q * 512.0f);      // denormal: d*2^-9, d in 1..7
    else         byte = (unsigned)((eq + 7) << 3) | ((uq >> 20) & 7u);
    return (unsigned char)(s | byte);
}

// Kernel 1: fp32 row norms + fp32->fp8 conversion into a PRE-SWIZZLED global
// layout: within each 32B k-slab of row r, 8B chunk c is stored at position
// c ^ ((r>>2)&3). This makes the GEMM's LDS staging a straight linear copy
// AND its frag reads bank-conflict-free (r7 measured 3072 conflicts/block
// from the unswizzled K-major layout). Swizzle bits depend only on r%16, so
// one layout serves every 128-row tile. One wave per row; lane packs 8 elems
// = exactly one 8B chunk (chunk id = lane&3, slab = lane>>2).
__global__ __launch_bounds__(256) void norm_convert_kernel(
    const float* __restrict__ X, unsigned char* __restrict__ Xq,
    float* __restrict__ norms, float* __restrict__ acc)
{
    const int tid  = threadIdx.x;
    const int lane = tid & 63;
    const int w    = tid >> 6;
    const int row  = blockIdx.x * 4 + w;

    if (blockIdx.x == 0 && tid < NACC) acc[tid] = 0.0f;

    const float* xr = X + (size_t)row * DIM + lane * 8;
    float4 v0 = *(const float4*)xr;
    float4 v1 = *(const float4*)(xr + 4);

    float s = 0.0f;
    s = fmaf(v0.x, v0.x, s); s = fmaf(v0.y, v0.y, s);
    s = fmaf(v0.z, v0.z, s); s = fmaf(v0.w, v0.w, s);
    s = fmaf(v1.x, v1.x, s); s = fmaf(v1.y, v1.y, s);
    s = fmaf(v1.z, v1.z, s); s = fmaf(v1.w, v1.w, s);

    union { unsigned char b[8]; uint2 v; } pk;
    pk.b[0] = f2e4m3(v0.x); pk.b[1] = f2e4m3(v0.y);
    pk.b[2] = f2e4m3(v0.z); pk.b[3] = f2e4m3(v0.w);
    pk.b[4] = f2e4m3(v1.x); pk.b[5] = f2e4m3(v1.y);
    pk.b[6] = f2e4m3(v1.z); pk.b[7] = f2e4m3(v1.w);

    // swizzled chunk position within the 32B slab
    const int slab = lane >> 2;
    const int cpos = (lane & 3) ^ ((row >> 2) & 3);
    *(uint2*)(Xq + (size_t)row * DIM + slab * 32 + cpos * 8) = pk.v;

    #pragma unroll
    for (int off = 32; off > 0; off >>= 1) s += __shfl_down(s, off, 64);
    if (lane == 0) norms[row] = s;
}

// Kernel 2: upper-triangular tiled X·X^T (fp8 e4m3 MFMA, bf16 rate) + fused
// sqrt/exp/sum epilogue. 128x128 tile/block, 4 waves, 64x64 quadrant/wave,
// BK=32 via 16x16x32_fp8_fp8.
//
// LDS: row-major 32B rows (4KB/tile), data arrives pre-swizzled from global.
//   staging write: thread -> row tid>>1, 16B half tid&1 (linear copy);
//     write quad (2r+h)%8 -> 8 distinct quads per 8-lane phase: conflict-free.
//   frag read: lane reads 8B at fr*32 + (q ^ ((fr>>2)&3))*8; each fr-quartet
//     gets distinct q^s -> all 32 banks exactly once per 16-lane phase: free.
//   Position q^s(row) holds k-chunk q (double-XOR cancels): semantics exact.
//
// 1-deep register-prefetch pipeline (verified; 2-deep spills at the 128-reg
// budget -> 160MB scratch, r4 measured). NO device-scope fences (r3: agent
// fence = per-XCD L2 flush, +40us).
__global__ __launch_bounds__(256, 4) void pair_loss_gemm_kernel(
    const unsigned char* __restrict__ Xq, const float* __restrict__ norms,
    float* __restrict__ acc)
{
    __shared__ __align__(16) char As0[4096];
    __shared__ __align__(16) char As1[4096];
    __shared__ __align__(16) char Bs0[4096];
    __shared__ __align__(16) char Bs1[4096];
    __shared__ float wsum[4];

    // decode linear block id -> upper-triangular (bi, bj), bi <= bj
    int t = blockIdx.x, bi = 0;
    while (t >= (NT - bi)) { t -= (NT - bi); bi++; }
    const int bj = bi + t;

    const int tid  = threadIdx.x;
    const int lane = tid & 63;
    const int w    = tid >> 6;

    const int rowA = bi * 128;
    const int rowB = bj * 128;

    f32x4 accv[4][4];
    const f32x4 zero = {0.0f, 0.0f, 0.0f, 0.0f};
    #pragma unroll
    for (int a = 0; a < 4; a++)
        #pragma unroll
        for (int b = 0; b < 4; b++) accv[a][b] = zero;

    // staging: thread -> row r0 = tid>>1, 16B-half h0 = tid&1 (linear copy;
    // global data is pre-swizzled, LDS layout = global slab layout).
    const int r0 = tid >> 1;
    const int h0 = tid & 1;
    const int wb = r0 * 32 + h0 * 16;            // LDS byte offset
    const unsigned char* gA = Xq + (size_t)(rowA + r0) * DIM + h0 * 16;
    const unsigned char* gB = Xq + (size_t)(rowB + r0) * DIM + h0 * 16;

    // MFMA fp8 frag: lane holds A[m=lane&15][k=q*8..q*8+7], q=lane>>4.
    // Swizzled position of chunk q in row fr: q ^ ((fr>>2)&3).
    const int fr = lane & 15;
    const int q  = lane >> 4;
    const int fo = fr * 32 + (q ^ ((fr >> 2) & 3)) * 8;
    const int wr = (w & 1) * 64;
    const int wc = (w >> 1) * 64;

    // prologue: stage slab 0 through registers
    {
        uint4 pa = *(const uint4*)gA;
        uint4 pb = *(const uint4*)gB;
        *(uint4*)(As0 + wb) = pa;
        *(uint4*)(Bs0 + wb) = pb;
    }
    __syncthreads();

    char* curA = As0; char* nxtA = As1;
    char* curB = Bs0; char* nxtB = Bs1;

    #pragma unroll 1
    for (int k = 0; k < 16; k++) {
        // prefetch next 32-byte K-slab into registers (in flight during MFMA)
        uint4 pa, pb;
        const bool more = (k < 15);
        if (more) {
            const int k0 = (k + 1) * 32;
            pa = *(const uint4*)(gA + k0);
            pb = *(const uint4*)(gB + k0);
        }

        long af[4], bf[4];
        #pragma unroll
        for (int a = 0; a < 4; a++)
            af[a] = *(const long*)(curA + (wr + a * 16) * 32 + fo);
        #pragma unroll
        for (int b = 0; b < 4; b++)
            bf[b] = *(const long*)(curB + (wc + b * 16) * 32 + fo);

        #pragma unroll
        for (int a = 0; a < 4; a++)
            #pragma unroll
            for (int b = 0; b < 4; b++)
                accv[a][b] = __builtin_amdgcn_mfma_f32_16x16x32_fp8_fp8(
                    af[a], bf[b], accv[a][b], 0, 0, 0);

        if (more) {
            *(uint4*)(nxtA + wb) = pa;   // vmcnt wait lands here, not barrier
            *(uint4*)(nxtB + wb) = pb;
            __syncthreads();
            char* tA = curA; curA = nxtA; nxtA = tA;
            char* tB = curB; curB = nxtB; nxtB = tB;
        }
    }

    // epilogue: term = exp(-0.1*sqrt(max(ni+nj-2*dot, 0))); diag -> 1
    // C/D layout: col = lane&15, row = (lane>>4)*4 + reg (dtype-independent)
    const float wgt = (bi == bj) ? 1.0f : 2.0f;
    float lsum = 0.0f;
    #pragma unroll
    for (int a = 0; a < 4; a++) {
        const int gi0 = rowA + wr + a * 16 + (lane >> 4) * 4;
        #pragma unroll
        for (int b = 0; b < 4; b++) {
            const int gj = rowB + wc + b * 16 + (lane & 15);
            const float nj = norms[gj];
            #pragma unroll
            for (int r = 0; r < 4; r++) {
                const int gi = gi0 + r;
                float sq = fmaf(-2.0f, accv[a][b][r], norms[gi] + nj);
                sq = fmaxf(sq, 0.0f);
                float term = __expf(-0.1f * sqrtf(sq));
                if (gi == gj) term = 1.0f;
                lsum += term;
            }
        }
    }
    lsum *= wgt;
    #pragma unroll
    for (int off = 32; off > 0; off >>= 1) lsum += __shfl_down(lsum, off, 64);
    if (lane == 0) wsum[w] = lsum;
    __syncthreads();
    if (tid == 0)
        atomicAdd(&acc[blockIdx.x & (NACC - 1)],
                  wsum[0] + wsum[1] + wsum[2] + wsum[3]);
}

// Kernel 3: finalize scalar outputs (sum NACC slots)
__global__ void finalize_kernel(const float* __restrict__ acc,
                                float* __restrict__ out)
{
    const int lane = threadIdx.x;
    float s = (lane < NACC) ? acc[lane] : 0.0f;
    #pragma unroll
    for (int off = 32; off > 0; off >>= 1) s += __shfl_down(s, off, 64);
    if (lane == 0) {
        const float inv = 1.0f / ((float)NROWS * (float)NROWS); // 2^-26 exact
        float loss = s * inv * 0.1f;
        out[0] = loss;
        out[1] = 0.5f * loss;
    }
}

extern "C" void kernel_launch(void* const* d_in, const int* in_sizes, int n_in,
                              void* d_out, int out_size, void* d_ws, size_t ws_size,
                              hipStream_t stream)
{
    const float* X = (const float*)d_in[0];
    float* out = (float*)d_out;

    char* ws = (char*)d_ws;
    float*         acc   = (float*)ws;                   // NACC fp32 slots
    float*         norms = (float*)(ws + 1024);          // 8192 fp32 (32 KB)
    unsigned char* Xq    = (unsigned char*)(ws + 1024 + 32768); // fp8 X, 4 MB

    norm_convert_kernel<<<NROWS / 4, 256, 0, stream>>>(X, Xq, norms, acc);
    pair_loss_gemm_kernel<<<NTRI, 256, 0, stream>>>(Xq, norms, acc);
    finalize_kernel<<<1, 64, 0, stream>>>(acc, out);
}

// Round 9
// 105.062 us; speedup vs baseline: 1.4876x; 1.0887x over previous
//
#include <hip/hip_runtime.h>

// Problem constants
#define NROWS 8192   // 4 * 2048
#define DIM   512
#define NT    64                    // 8192 / 128 tiles per side
#define NTRI  (NT * (NT + 1) / 2)   // 2080 upper-triangular tile blocks
#define NACC  64                    // accumulator slots (contention spread)

using f32x4 = __attribute__((ext_vector_type(4))) float;

// Software fp32 -> OCP e4m3fn, round-to-nearest-even (fp8 cvt builtin was the
// r6 crash suspect; this SW encoder is r7/r8-verified, absmax passed).
__device__ __forceinline__ unsigned char f2e4m3(float x) {
    unsigned ux = __float_as_uint(x);
    unsigned s  = (ux >> 24) & 0x80u;
    float a = __uint_as_float(ux & 0x7FFFFFFFu);     // |x|, finite for our data
    a = fminf(a, 448.0f);                            // clamp to max finite
    unsigned ua = __float_as_uint(a);
    int eb = (int)(ua >> 23);                        // biased exponent
    if (eb < 121) eb = 121;                          // denormal region: step 2^-9
    float step  = __uint_as_float((unsigned)(eb - 3) << 23);    // 2^(eb-130)
    float istep = __uint_as_float((unsigned)(257 - eb) << 23);  // 2^(130-eb), exact
    float q = rintf(a * istep) * step;               // RNE on e4m3 grid
    q = fminf(q, 448.0f);
    if (q < 0.001953125f)                            // below min denormal 2^-9 -> 0
        return (unsigned char)s;
    unsigned uq = __float_as_uint(q);
    int eq = (int)(uq >> 23) - 127;
    unsigned byte;
    if (eq < -6) byte = (unsigned)(q * 512.0f);      // denormal: d*2^-9, d in 1..7
    else         byte = (unsigned)((eq + 7) << 3) | ((uq >> 20) & 7u);
    return (unsigned char)(s | byte);
}

// Kernel 1: fp32 row norms + fp32->fp8 conversion into a pre-swizzled global
// layout for BK=64 tiles: within each 64B k-slab of row r, 8B chunk c is
// stored at position c ^ (r&7). GEMM staging then stays a straight linear
// copy and frag reads are <=2-way in LDS (free). One wave per row; a lane's
// 8 elems = exactly one 8B chunk (chunk = lane&7, slab = lane>>3).
__global__ __launch_bounds__(256) void norm_convert_kernel(
    const float* __restrict__ X, unsigned char* __restrict__ Xq,
    float* __restrict__ norms, float* __restrict__ acc)
{
    const int tid  = threadIdx.x;
    const int lane = tid & 63;
    const int w    = tid >> 6;
    const int row  = blockIdx.x * 4 + w;

    if (blockIdx.x == 0 && tid < NACC) acc[tid] = 0.0f;

    const float* xr = X + (size_t)row * DIM + lane * 8;
    float4 v0 = *(const float4*)xr;
    float4 v1 = *(const float4*)(xr + 4);

    float s = 0.0f;
    s = fmaf(v0.x, v0.x, s); s = fmaf(v0.y, v0.y, s);
    s = fmaf(v0.z, v0.z, s); s = fmaf(v0.w, v0.w, s);
    s = fmaf(v1.x, v1.x, s); s = fmaf(v1.y, v1.y, s);
    s = fmaf(v1.z, v1.z, s); s = fmaf(v1.w, v1.w, s);

    union { unsigned char b[8]; uint2 v; } pk;
    pk.b[0] = f2e4m3(v0.x); pk.b[1] = f2e4m3(v0.y);
    pk.b[2] = f2e4m3(v0.z); pk.b[3] = f2e4m3(v0.w);
    pk.b[4] = f2e4m3(v1.x); pk.b[5] = f2e4m3(v1.y);
    pk.b[6] = f2e4m3(v1.z); pk.b[7] = f2e4m3(v1.w);

    const int slab = lane >> 3;                      // 64B slab index (0..7)
    const int cpos = (lane & 7) ^ (row & 7);         // swizzled 8B position
    *(uint2*)(Xq + (size_t)row * DIM + slab * 64 + cpos * 8) = pk.v;

    #pragma unroll
    for (int off = 32; off > 0; off >>= 1) s += __shfl_down(s, off, 64);
    if (lane == 0) norms[row] = s;
}

// Kernel 2: upper-triangular tiled X·X^T (fp8 e4m3 MFMA) + fused sqrt/exp/sum
// epilogue. 128x128 tile/block, 4 waves, 64x64 quadrant/wave.
//
// BK=64 (r8 analysis: cost is per-iteration serialization, ~4.3k cyc wall vs
// ~400 cyc work/iter; halving data width bought only 6% -> halve ITERATIONS):
// 8 iterations of two 16x16x32 k-steps; prefetch lookahead budget doubles,
// barrier count halves.
//
// Registers: 64 acc + 16 prefetch + 16 frag + ~15 addr ~= 111 < 128 ->
// no spill at (256,4) (r4: 2-deep pipeline spilled -> 160MB scratch).
// LDS: 128 rows x 64B x 2 matrices x 2 buffers = 32KB; global data arrives
// pre-swizzled (chunk c of row r at c^(r&7)) -> staging writes and frag
// reads both <=2-way (free, m136; r8 confirmed 0 conflicts w/ this scheme).
// NO device-scope fences (r3: agent fence = per-XCD L2 flush, +40us).
__global__ __launch_bounds__(256, 4) void pair_loss_gemm_kernel(
    const unsigned char* __restrict__ Xq, const float* __restrict__ norms,
    float* __restrict__ acc)
{
    __shared__ __align__(16) char As0[8192];
    __shared__ __align__(16) char As1[8192];
    __shared__ __align__(16) char Bs0[8192];
    __shared__ __align__(16) char Bs1[8192];
    __shared__ float wsum[4];

    // decode linear block id -> upper-triangular (bi, bj), bi <= bj
    int t = blockIdx.x, bi = 0;
    while (t >= (NT - bi)) { t -= (NT - bi); bi++; }
    const int bj = bi + t;

    const int tid  = threadIdx.x;
    const int lane = tid & 63;
    const int w    = tid >> 6;

    const int rowA = bi * 128;
    const int rowB = bj * 128;

    f32x4 accv[4][4];
    const f32x4 zero = {0.0f, 0.0f, 0.0f, 0.0f};
    #pragma unroll
    for (int a = 0; a < 4; a++)
        #pragma unroll
        for (int b = 0; b < 4; b++) accv[a][b] = zero;

    // staging: thread -> row r0 = tid>>1, 32B half h0 = tid&1 of the 64B slab.
    // 2 uint4 per matrix per iter (linear copy; data pre-swizzled in global).
    const int r0 = tid >> 1;
    const int h0 = tid & 1;
    const int wb = r0 * 64 + h0 * 32;            // LDS byte offset
    const unsigned char* gA = Xq + (size_t)(rowA + r0) * DIM + h0 * 32;
    const unsigned char* gB = Xq + (size_t)(rowB + r0) * DIM + h0 * 32;

    // MFMA fp8 frag: lane holds A[m=fr][k=q*8..q*8+7] per k-step, q=lane>>4.
    // Chunk index in the 64B slab: kstep*4+q, at swizzled position ^(fr&7).
    // fo1 = fo0 ^ 32 (chunk-bit2 <-> byte-bit5).
    const int fr  = lane & 15;
    const int q   = lane >> 4;
    const int fo0 = fr * 64 + ((q ^ (fr & 7)) * 8);
    const int wr  = (w & 1) * 64;
    const int wc  = (w >> 1) * 64;

    // prologue: stage slab 0 through registers
    {
        uint4 pa0 = *(const uint4*)gA;
        uint4 pa1 = *(const uint4*)(gA + 16);
        uint4 pb0 = *(const uint4*)gB;
        uint4 pb1 = *(const uint4*)(gB + 16);
        *(uint4*)(As0 + wb)      = pa0;
        *(uint4*)(As0 + wb + 16) = pa1;
        *(uint4*)(Bs0 + wb)      = pb0;
        *(uint4*)(Bs0 + wb + 16) = pb1;
    }
    __syncthreads();

    char* curA = As0; char* nxtA = As1;
    char* curB = Bs0; char* nxtB = Bs1;

    #pragma unroll 1
    for (int k = 0; k < 8; k++) {
        // prefetch next 64B K-slab into registers (in flight across 2 k-steps)
        uint4 pa0, pa1, pb0, pb1;
        const bool more = (k < 7);
        if (more) {
            const int k0 = (k + 1) * 64;
            pa0 = *(const uint4*)(gA + k0);
            pa1 = *(const uint4*)(gA + k0 + 16);
            pb0 = *(const uint4*)(gB + k0);
            pb1 = *(const uint4*)(gB + k0 + 16);
        }

        #pragma unroll
        for (int s = 0; s < 2; s++) {
            const int fo = fo0 ^ (s << 5);
            long af[4], bf[4];
            #pragma unroll
            for (int a = 0; a < 4; a++)
                af[a] = *(const long*)(curA + (wr + a * 16) * 64 + fo);
            #pragma unroll
            for (int b = 0; b < 4; b++)
                bf[b] = *(const long*)(curB + (wc + b * 16) * 64 + fo);
            #pragma unroll
            for (int a = 0; a < 4; a++)
                #pragma unroll
                for (int b = 0; b < 4; b++)
                    accv[a][b] = __builtin_amdgcn_mfma_f32_16x16x32_fp8_fp8(
                        af[a], bf[b], accv[a][b], 0, 0, 0);
        }

        if (more) {
            *(uint4*)(nxtA + wb)      = pa0;  // vmcnt wait lands here
            *(uint4*)(nxtA + wb + 16) = pa1;
            *(uint4*)(nxtB + wb)      = pb0;
            *(uint4*)(nxtB + wb + 16) = pb1;
            __syncthreads();
            char* tA = curA; curA = nxtA; nxtA = tA;
            char* tB = curB; curB = nxtB; nxtB = tB;
        }
    }

    // epilogue: term = exp(-0.1*sqrt(max(ni+nj-2*dot, 0))); diag -> 1
    // C/D layout: col = lane&15, row = (lane>>4)*4 + reg (dtype-independent)
    const float wgt = (bi == bj) ? 1.0f : 2.0f;
    float lsum = 0.0f;
    #pragma unroll
    for (int a = 0; a < 4; a++) {
        const int gi0 = rowA + wr + a * 16 + (lane >> 4) * 4;
        #pragma unroll
        for (int b = 0; b < 4; b++) {
            const int gj = rowB + wc + b * 16 + (lane & 15);
            const float nj = norms[gj];
            #pragma unroll
            for (int r = 0; r < 4; r++) {
                const int gi = gi0 + r;
                float sq = fmaf(-2.0f, accv[a][b][r], norms[gi] + nj);
                sq = fmaxf(sq, 0.0f);
                float term = __expf(-0.1f * sqrtf(sq));
                if (gi == gj) term = 1.0f;
                lsum += term;
            }
        }
    }
    lsum *= wgt;
    #pragma unroll
    for (int off = 32; off > 0; off >>= 1) lsum += __shfl_down(lsum, off, 64);
    if (lane == 0) wsum[w] = lsum;
    __syncthreads();
    if (tid == 0)
        atomicAdd(&acc[blockIdx.x & (NACC - 1)],
                  wsum[0] + wsum[1] + wsum[2] + wsum[3]);
}

// Kernel 3: finalize scalar outputs (sum NACC slots)
__global__ void finalize_kernel(const float* __restrict__ acc,
                                float* __restrict__ out)
{
    const int lane = threadIdx.x;
    float s = (lane < NACC) ? acc[lane] : 0.0f;
    #pragma unroll
    for (int off = 32; off > 0; off >>= 1) s += __shfl_down(s, off, 64);
    if (lane == 0) {
        const float inv = 1.0f / ((float)NROWS * (float)NROWS); // 2^-26 exact
        float loss = s * inv * 0.1f;
        out[0] = loss;
        out[1] = 0.5f * loss;
    }
}

extern "C" void kernel_launch(void* const* d_in, const int* in_sizes, int n_in,
                              void* d_out, int out_size, void* d_ws, size_t ws_size,
                              hipStream_t stream)
{
    const float* X = (const float*)d_in[0];
    float* out = (float*)d_out;

    char* ws = (char*)d_ws;
    float*         acc   = (float*)ws;                   // NACC fp32 slots
    float*         norms = (float*)(ws + 1024);          // 8192 fp32 (32 KB)
    unsigned char* Xq    = (unsigned char*)(ws + 1024 + 32768); // fp8 X, 4 MB

    norm_convert_kernel<<<NROWS / 4, 256, 0, stream>>>(X, Xq, norms, acc);
    pair_loss_gemm_kernel<<<NTRI, 256, 0, stream>>>(Xq, norms, acc);
    finalize_kernel<<<1, 64, 0, stream>>>(acc, out);
}